// Round 12
// baseline (165.572 us; speedup 1.0000x reference)
//
#include <hip/hip_runtime.h>
#include <stdint.h>

#define B_   2
#define S_   2048
#define H_   8
#define D_   64
#define HID_ 512
#define W_   128
#define M_   (B_ * S_)       // 4096 rows for all GEMMs
#define E_   (M_ * HID_)     // 2,097,152 elems per activation matrix
#define PPAD_ 72             // u16 row stride of P LDS tiles
#define AOP_ 520             // u16 row stride of AO LDS tile (bank-stagger)
#define M0_  12.0f           // fixed softmax max (scaled scores ~N(0,1), max ≲ 6)

typedef unsigned short u16;
typedef __attribute__((ext_vector_type(8))) __bf16 bf16x8;
typedef __attribute__((ext_vector_type(4))) float  floatx4;

__device__ __forceinline__ float b2f(u16 u) {
    union { unsigned int i; float f; } x;
    x.i = ((unsigned int)u) << 16;
    return x.f;
}
__device__ __forceinline__ u16 f2b(float f) {
    union { float f; unsigned int i; } x;
    x.f = f;
    unsigned int r = x.i + 0x7FFFu + ((x.i >> 16) & 1u);  // RNE
    return (u16)(r >> 16);
}

// convert 8 fp32 -> 8 bf16 (HW RNE)
__device__ __forceinline__ bf16x8 cvt8(float4 a, float4 b) {
    bf16x8 v;
    v[0] = (__bf16)a.x; v[1] = (__bf16)a.y; v[2] = (__bf16)a.z; v[3] = (__bf16)a.w;
    v[4] = (__bf16)b.x; v[5] = (__bf16)b.y; v[6] = (__bf16)b.z; v[7] = (__bf16)b.w;
    return v;
}
__device__ __forceinline__ void cvt8_store(float4 a, float4 b, u16* dst) {
    *(bf16x8*)dst = cvt8(a, b);
}

// ---------------------------------------------------------------------------
// QKV GEMM with inline fp32->bf16 conversion (unchanged from R11).
// C = X @ W^T + bias; tile 128m x 64n / 2 waves / BK=32.
// MODE 1: u16 hi plane, [(b*H+h)*S + s]*D + d      (Q,K for attn frags)
// MODE 2: u16 hi plane, [(b*H+h)*D + d]*S + s      (V^T for attn B frags)
template <int MODE>
__device__ __forceinline__ void gemm_fp32in_body(
    const float* __restrict__ Xf, const float* __restrict__ Wf,
    const float* __restrict__ bias, u16* __restrict__ outH) {
    __shared__ u16 As[128 * 32];
    __shared__ u16 Bs[64 * 32];

    const int tid  = threadIdx.x;
    const int wave = tid >> 6;
    const int lane = tid & 63;
    const int r16  = lane & 15;
    const int quad = lane >> 4;
    const int m0 = blockIdx.x * 128;
    const int n0 = blockIdx.y * 64;
    const int m_base = m0 + wave * 64;

    const int ar = tid >> 2;          // A staging: row within 32-row batch
    const int ak = (tid & 3) * 8;     // A staging: elem offset in 32-k row
    const int br = tid >> 1;          // B staging: row 0..63
    const int bk2 = (tid & 1) * 16;   // B staging: elem offset

    floatx4 zero = {0.f, 0.f, 0.f, 0.f};
    floatx4 acc[4][4];
#pragma unroll
    for (int i = 0; i < 4; i++)
#pragma unroll
        for (int j = 0; j < 4; j++) acc[i][j] = zero;

    for (int k0 = 0; k0 < HID_; k0 += 32) {
        __syncthreads();
#pragma unroll
        for (int e = 0; e < 4; e++) {
            const int row = e * 32 + ar;
            const float4* src = (const float4*)(Xf + (size_t)(m0 + row) * HID_ + k0 + ak);
            cvt8_store(src[0], src[1], &As[row * 32 + ak]);
        }
        {
            const float4* src = (const float4*)(Wf + (size_t)(n0 + br) * HID_ + k0 + bk2);
            cvt8_store(src[0], src[1], &Bs[br * 32 + bk2]);
            cvt8_store(src[2], src[3], &Bs[br * 32 + bk2 + 8]);
        }
        __syncthreads();

        bf16x8 a0[4], b[4];
#pragma unroll
        for (int t = 0; t < 4; t++) {
            a0[t] = *(const bf16x8*)&As[(wave * 64 + t * 16 + r16) * 32 + quad * 8];
            b[t]  = *(const bf16x8*)&Bs[(t * 16 + r16) * 32 + quad * 8];
        }
#pragma unroll
        for (int i = 0; i < 4; i++)
#pragma unroll
            for (int j = 0; j < 4; j++)
                acc[i][j] = __builtin_amdgcn_mfma_f32_16x16x32_bf16(a0[i], b[j], acc[i][j], 0, 0, 0);
    }

    // C/D: col = lane&15, row = quad*4 + reg
    const int bb = m_base >> 11;
    if (MODE == 1) {
#pragma unroll
        for (int j = 0; j < 4; j++) {
            const int col = n0 + j * 16 + r16;
            const int h = col >> 6, d = col & (D_ - 1);
            const float bv = bias[col];
            const size_t base = (size_t)(bb * H_ + h) * S_;
#pragma unroll
            for (int i = 0; i < 4; i++)
#pragma unroll
                for (int r = 0; r < 4; r++) {
                    const int s = (m_base & (S_ - 1)) + i * 16 + quad * 4 + r;
                    outH[(base + s) * D_ + d] = f2b(acc[i][j][r] + bv);
                }
        }
    } else {
#pragma unroll
        for (int j = 0; j < 4; j++) {
            const int col = n0 + j * 16 + r16;
            const int h = col >> 6, d = col & (D_ - 1);
            const float bv = bias[col];
            const size_t base = ((size_t)(bb * H_ + h) * D_ + d) * S_;
            const int s0 = (m_base & (S_ - 1)) + quad * 4;
#pragma unroll
            for (int i = 0; i < 4; i++) {
                ushort4 hs;
                hs.x = f2b(acc[i][j][0] + bv);
                hs.y = f2b(acc[i][j][1] + bv);
                hs.z = f2b(acc[i][j][2] + bv);
                hs.w = f2b(acc[i][j][3] + bv);
                *(ushort4*)(outH + base + s0 + i * 16) = hs;
            }
        }
    }
}

__global__ __launch_bounds__(128) void qkv_fused_kernel(
    const float* __restrict__ xq, const float* __restrict__ xk, const float* __restrict__ xv,
    const float* __restrict__ wq, const float* __restrict__ wk, const float* __restrict__ wv,
    const float* __restrict__ bq, const float* __restrict__ bk, const float* __restrict__ bv,
    u16* __restrict__ P) {   // P planes: Qh,Kh ([B,H,S,D]), Vth ([B,H,D,S])
    if (blockIdx.z == 0)      gemm_fp32in_body<1>(xq, wq, bq, P);
    else if (blockIdx.z == 1) gemm_fp32in_body<1>(xk, wk, bk, P + E_);
    else                      gemm_fp32in_body<2>(xv, wv, bv, P + 2 * (size_t)E_);
}

// ---------------------------------------------------------------------------
// Fused attention + output projection. One block = (batch b, 64-query stripe).
// 512 threads = 8 waves, ONE WAVE PER HEAD (no cross-wave O reduction).
// Phase A: per-head windowed attention (fixed-max softmax, bf16 MFMA, R7-proven
//          math), normalized AO tile [64 q][512 hid] kept in LDS as bf16.
// Phase B: out = AO @ Wo^T + bo; wave w computes the 64-wide column tile
//          n0 = w*64; A-frags from LDS AO, B-frags cvt'd from fp32 Wo (L2-hot).
// LDS: Ps 8*64*72*2 = 73728 B + AO 64*520*2 = 66560 B = 140288 B (gfx950: 160K).
__global__ __launch_bounds__(512) void attn_out_kernel(
    const u16* __restrict__ Qh, const u16* __restrict__ Kh,
    const u16* __restrict__ Vth,
    const float* __restrict__ Wo, const float* __restrict__ bo,
    float* __restrict__ out) {
    __shared__ u16 Ps[8][64][PPAD_];   // per-wave(=head) P tile [q][k]
    __shared__ u16 AO[64][AOP_];       // normalized attention output, bf16

    const int tid  = threadIdx.x;
    const int wave = tid >> 6;         // head index
    const int lane = tid & 63;
    const int r16 = lane & 15, quad = lane >> 4;
    const int qt = blockIdx.x, b = blockIdx.y;
    const int q0 = qt * 64;
    const int bh = b * H_ + wave;
    const size_t sd = (size_t)bh * S_ * D_;
    const size_t ds = (size_t)bh * D_ * S_;

    // ---- Phase A: attention for head `wave` ----
    bf16x8 qf[2][4];
#pragma unroll
    for (int ks = 0; ks < 2; ks++)
#pragma unroll
        for (int i = 0; i < 4; i++)
            qf[ks][i] = *(const bf16x8*)(Qh + sd + (size_t)(q0 + i * 16 + r16) * D_ + ks * 32 + quad * 8);

    floatx4 zero = {0.f, 0.f, 0.f, 0.f};
    floatx4 O[4][4];
    float lsum[4][4];
#pragma unroll
    for (int i = 0; i < 4; i++)
#pragma unroll
        for (int j = 0; j < 4; j++) O[i][j] = zero;
#pragma unroll
    for (int i = 0; i < 4; i++)
#pragma unroll
        for (int r = 0; r < 4; r++) lsum[i][r] = 0.f;

    int t_lo = qt - 2; if (t_lo < 0) t_lo = 0;
    int t_hi = qt + 2; if (t_hi > S_ / 64 - 1) t_hi = S_ / 64 - 1;

    for (int t = t_lo; t <= t_hi; t++) {
        const int k0 = t * 64;
        floatx4 sa[4][4];
#pragma unroll
        for (int i = 0; i < 4; i++)
#pragma unroll
            for (int j = 0; j < 4; j++) sa[i][j] = zero;

#pragma unroll
        for (int ks = 0; ks < 2; ks++) {
            bf16x8 kf[4];
#pragma unroll
            for (int j = 0; j < 4; j++)
                kf[j] = *(const bf16x8*)(Kh + sd + (size_t)(k0 + j * 16 + r16) * D_ + ks * 32 + quad * 8);
#pragma unroll
            for (int i = 0; i < 4; i++)
#pragma unroll
                for (int j = 0; j < 4; j++)
                    sa[i][j] = __builtin_amdgcn_mfma_f32_16x16x32_bf16(qf[ks][i], kf[j], sa[i][j], 0, 0, 0);
        }

        // p = exp(s/8 - M0) with band mask; per-lane row partials; P -> LDS
#pragma unroll
        for (int i = 0; i < 4; i++)
#pragma unroll
            for (int j = 0; j < 4; j++) {
                const int kc = k0 + j * 16 + r16;
#pragma unroll
                for (int r = 0; r < 4; r++) {
                    const int q = q0 + i * 16 + quad * 4 + r;
                    const bool valid = (unsigned)(kc - q + W_) <= (unsigned)(2 * W_);
                    const float p = valid ? __expf(fmaf(sa[i][j][r], 0.125f, -M0_)) : 0.f;
                    lsum[i][r] += p;
                    Ps[wave][i * 16 + quad * 4 + r][j * 16 + r16] = f2b(p);
                }
            }
        // DS ops in-order per wave: Ps write->read within this wave is safe.

#pragma unroll
        for (int ks = 0; ks < 2; ks++) {
            bf16x8 pf[4], vf[4];
#pragma unroll
            for (int i = 0; i < 4; i++)
                pf[i] = *(const bf16x8*)&Ps[wave][i * 16 + r16][ks * 32 + quad * 8];
#pragma unroll
            for (int j = 0; j < 4; j++)
                vf[j] = *(const bf16x8*)(Vth + ds + (size_t)(j * 16 + r16) * S_ + k0 + ks * 32 + quad * 8);
#pragma unroll
            for (int i = 0; i < 4; i++)
#pragma unroll
                for (int j = 0; j < 4; j++)
                    O[i][j] = __builtin_amdgcn_mfma_f32_16x16x32_bf16(pf[i], vf[j], O[i][j], 0, 0, 0);
        }
    }

    // row-sum reduce over the 16 r16 lanes (bits 0-3 of lane)
    float inv[4][4];
#pragma unroll
    for (int i = 0; i < 4; i++)
#pragma unroll
        for (int r = 0; r < 4; r++) {
            float l = lsum[i][r];
#pragma unroll
            for (int off = 1; off < 16; off <<= 1) l += __shfl_xor(l, off, 64);
            inv[i][r] = 1.f / l;
        }

    // normalized AO tile -> LDS (bf16).  q row = i*16+quad*4+r, col = wave*64+j*16+r16
#pragma unroll
    for (int i = 0; i < 4; i++)
#pragma unroll
        for (int j = 0; j < 4; j++)
#pragma unroll
            for (int r = 0; r < 4; r++)
                AO[i * 16 + quad * 4 + r][wave * 64 + j * 16 + r16] =
                    f2b(O[i][j][r] * inv[i][r]);

    __syncthreads();   // AO complete

    // ---- Phase B: out tile [q0..q0+64) x [wave*64 .. +64) ----
    const int n0 = wave * 64;
    floatx4 acc[4][4];
#pragma unroll
    for (int i = 0; i < 4; i++)
#pragma unroll
        for (int j = 0; j < 4; j++) acc[i][j] = zero;

    for (int k0 = 0; k0 < HID_; k0 += 32) {
        bf16x8 af[4], bfr[4];
#pragma unroll
        for (int i = 0; i < 4; i++)
            af[i] = *(const bf16x8*)&AO[i * 16 + r16][k0 + quad * 8];
#pragma unroll
        for (int j = 0; j < 4; j++) {
            const float4* wp = (const float4*)(Wo + (size_t)(n0 + j * 16 + r16) * HID_ + k0 + quad * 8);
            bfr[j] = cvt8(wp[0], wp[1]);
        }
#pragma unroll
        for (int i = 0; i < 4; i++)
#pragma unroll
            for (int j = 0; j < 4; j++)
                acc[i][j] = __builtin_amdgcn_mfma_f32_16x16x32_bf16(af[i], bfr[j], acc[i][j], 0, 0, 0);
    }

#pragma unroll
    for (int j = 0; j < 4; j++) {
        const int col = n0 + j * 16 + r16;
        const float bv = bo[col];
#pragma unroll
        for (int i = 0; i < 4; i++) {
            const int row = q0 + i * 16 + quad * 4;
#pragma unroll
            for (int r = 0; r < 4; r++)
                out[(size_t)(b * S_ + row + r) * HID_ + col] = acc[i][j][r] + bv;
        }
    }
}

extern "C" void kernel_launch(void* const* d_in, const int* in_sizes, int n_in,
                              void* d_out, int out_size, void* d_ws, size_t ws_size,
                              hipStream_t stream) {
    const float* value = (const float*)d_in[0];
    const float* key_  = (const float*)d_in[1];
    const float* query = (const float*)d_in[2];
    const float* Wq = (const float*)d_in[3];
    const float* bq = (const float*)d_in[4];
    const float* Wk = (const float*)d_in[5];
    const float* bk = (const float*)d_in[6];
    const float* Wv = (const float*)d_in[7];
    const float* bv = (const float*)d_in[8];
    const float* Wo = (const float*)d_in[9];
    const float* bo = (const float*)d_in[10];

    // workspace (u16), 3E = 12 MB: Qh, Kh ([B,H,S,D]), Vth ([B,H,D,S])
    u16* P = (u16*)d_ws;

    qkv_fused_kernel<<<dim3(M_ / 128, HID_ / 64, 3), 128, 0, stream>>>(
        query, key_, value, Wq, Wk, Wv, bq, bk, bv, P);
    attn_out_kernel<<<dim3(S_ / 64, B_), 512, 0, stream>>>(
        P, P + E_, P + 2 * (size_t)E_, Wo, bo, (float*)d_out);
}

// Round 13
// 161.172 us; speedup vs baseline: 1.0273x; 1.0273x over previous
//
#include <hip/hip_runtime.h>
#include <stdint.h>

#define B_   2
#define S_   2048
#define H_   8
#define D_   64
#define HID_ 512
#define W_   128
#define M_   (B_ * S_)       // 4096 rows for all GEMMs
#define E_   (M_ * HID_)     // 2,097,152 elems per activation matrix
#define PPAD_ 72             // u16 row stride of P LDS tiles
#define AOP_ 520             // u16 row stride of AO LDS tile (bank-stagger)
#define M0_  12.0f           // fixed softmax max (scaled scores ~N(0,1), max ≲ 6)
#define TQ_  16              // queries per block (parallelism: 256 blocks)

typedef unsigned short u16;
typedef __attribute__((ext_vector_type(8))) __bf16 bf16x8;
typedef __attribute__((ext_vector_type(4))) float  floatx4;

__device__ __forceinline__ float b2f(u16 u) {
    union { unsigned int i; float f; } x;
    x.i = ((unsigned int)u) << 16;
    return x.f;
}
__device__ __forceinline__ u16 f2b(float f) {
    union { float f; unsigned int i; } x;
    x.f = f;
    unsigned int r = x.i + 0x7FFFu + ((x.i >> 16) & 1u);  // RNE
    return (u16)(r >> 16);
}

// convert 8 fp32 -> 8 bf16 (HW RNE)
__device__ __forceinline__ bf16x8 cvt8(float4 a, float4 b) {
    bf16x8 v;
    v[0] = (__bf16)a.x; v[1] = (__bf16)a.y; v[2] = (__bf16)a.z; v[3] = (__bf16)a.w;
    v[4] = (__bf16)b.x; v[5] = (__bf16)b.y; v[6] = (__bf16)b.z; v[7] = (__bf16)b.w;
    return v;
}
__device__ __forceinline__ void cvt8_store(float4 a, float4 b, u16* dst) {
    *(bf16x8*)dst = cvt8(a, b);
}

// ---------------------------------------------------------------------------
// QKV GEMM with inline fp32->bf16 conversion (R11 verbatim, proven 149.7).
// C = X @ W^T + bias; tile 128m x 64n / 2 waves / BK=32.
// MODE 1: u16 hi plane, [(b*H+h)*S + s]*D + d      (Q,K for attn frags)
// MODE 2: u16 hi plane, [(b*H+h)*D + d]*S + s      (V^T for attn B frags)
template <int MODE>
__device__ __forceinline__ void gemm_fp32in_body(
    const float* __restrict__ Xf, const float* __restrict__ Wf,
    const float* __restrict__ bias, u16* __restrict__ outH) {
    __shared__ u16 As[128 * 32];
    __shared__ u16 Bs[64 * 32];

    const int tid  = threadIdx.x;
    const int wave = tid >> 6;
    const int lane = tid & 63;
    const int r16  = lane & 15;
    const int quad = lane >> 4;
    const int m0 = blockIdx.x * 128;
    const int n0 = blockIdx.y * 64;
    const int m_base = m0 + wave * 64;

    const int ar = tid >> 2;          // A staging: row within 32-row batch
    const int ak = (tid & 3) * 8;     // A staging: elem offset in 32-k row
    const int br = tid >> 1;          // B staging: row 0..63
    const int bk2 = (tid & 1) * 16;   // B staging: elem offset

    floatx4 zero = {0.f, 0.f, 0.f, 0.f};
    floatx4 acc[4][4];
#pragma unroll
    for (int i = 0; i < 4; i++)
#pragma unroll
        for (int j = 0; j < 4; j++) acc[i][j] = zero;

    for (int k0 = 0; k0 < HID_; k0 += 32) {
        __syncthreads();
#pragma unroll
        for (int e = 0; e < 4; e++) {
            const int row = e * 32 + ar;
            const float4* src = (const float4*)(Xf + (size_t)(m0 + row) * HID_ + k0 + ak);
            cvt8_store(src[0], src[1], &As[row * 32 + ak]);
        }
        {
            const float4* src = (const float4*)(Wf + (size_t)(n0 + br) * HID_ + k0 + bk2);
            cvt8_store(src[0], src[1], &Bs[br * 32 + bk2]);
            cvt8_store(src[2], src[3], &Bs[br * 32 + bk2 + 8]);
        }
        __syncthreads();

        bf16x8 a0[4], b[4];
#pragma unroll
        for (int t = 0; t < 4; t++) {
            a0[t] = *(const bf16x8*)&As[(wave * 64 + t * 16 + r16) * 32 + quad * 8];
            b[t]  = *(const bf16x8*)&Bs[(t * 16 + r16) * 32 + quad * 8];
        }
#pragma unroll
        for (int i = 0; i < 4; i++)
#pragma unroll
            for (int j = 0; j < 4; j++)
                acc[i][j] = __builtin_amdgcn_mfma_f32_16x16x32_bf16(a0[i], b[j], acc[i][j], 0, 0, 0);
    }

    // C/D: col = lane&15, row = quad*4 + reg
    const int bb = m_base >> 11;
    if (MODE == 1) {
#pragma unroll
        for (int j = 0; j < 4; j++) {
            const int col = n0 + j * 16 + r16;
            const int h = col >> 6, d = col & (D_ - 1);
            const float bv = bias[col];
            const size_t base = (size_t)(bb * H_ + h) * S_;
#pragma unroll
            for (int i = 0; i < 4; i++)
#pragma unroll
                for (int r = 0; r < 4; r++) {
                    const int s = (m_base & (S_ - 1)) + i * 16 + quad * 4 + r;
                    outH[(base + s) * D_ + d] = f2b(acc[i][j][r] + bv);
                }
        }
    } else {
#pragma unroll
        for (int j = 0; j < 4; j++) {
            const int col = n0 + j * 16 + r16;
            const int h = col >> 6, d = col & (D_ - 1);
            const float bv = bias[col];
            const size_t base = ((size_t)(bb * H_ + h) * D_ + d) * S_;
            const int s0 = (m_base & (S_ - 1)) + quad * 4;
#pragma unroll
            for (int i = 0; i < 4; i++) {
                ushort4 hs;
                hs.x = f2b(acc[i][j][0] + bv);
                hs.y = f2b(acc[i][j][1] + bv);
                hs.z = f2b(acc[i][j][2] + bv);
                hs.w = f2b(acc[i][j][3] + bv);
                *(ushort4*)(outH + base + s0 + i * 16) = hs;
            }
        }
    }
}

__global__ __launch_bounds__(128) void qkv_fused_kernel(
    const float* __restrict__ xq, const float* __restrict__ xk, const float* __restrict__ xv,
    const float* __restrict__ wq, const float* __restrict__ wk, const float* __restrict__ wv,
    const float* __restrict__ bq, const float* __restrict__ bk, const float* __restrict__ bv,
    u16* __restrict__ P) {   // P planes: Qh,Kh ([B,H,S,D]), Vth ([B,H,D,S])
    if (blockIdx.z == 0)      gemm_fp32in_body<1>(xq, wq, bq, P);
    else if (blockIdx.z == 1) gemm_fp32in_body<1>(xk, wk, bk, P + E_);
    else                      gemm_fp32in_body<2>(xv, wv, bv, P + 2 * (size_t)E_);
}

// ---------------------------------------------------------------------------
// Fused attention + output projection, TQ=16 queries per block.
// Grid (S/16, B) = 256 blocks; 512 threads = 8 waves, ONE WAVE PER HEAD.
// Phase A: per-head windowed attention (fixed-max softmax, bf16 MFMA; R7 math
//          with the i-loop collapsed to one 16-row group), normalized AO tile
//          [16 q][512 hid] in LDS as bf16.
// Phase B: out = AO @ Wo^T + bo; wave w computes columns [w*64, w*64+64),
//          A-frags from LDS AO, B-frags cvt'd from fp32 Wo (L2-hot).
// LDS: Ps 8*16*72*2 = 18432 B + AO 16*520*2 = 16640 B = 35072 B.
__global__ __launch_bounds__(512) void attn_out_kernel(
    const u16* __restrict__ Qh, const u16* __restrict__ Kh,
    const u16* __restrict__ Vth,
    const float* __restrict__ Wo, const float* __restrict__ bo,
    float* __restrict__ out) {
    __shared__ u16 Ps[8][TQ_][PPAD_];  // per-wave(=head) P tile [q][k]
    __shared__ u16 AO[TQ_][AOP_];      // normalized attention output, bf16

    const int tid  = threadIdx.x;
    const int wave = tid >> 6;         // head index
    const int lane = tid & 63;
    const int r16 = lane & 15, quad = lane >> 4;
    const int qt = blockIdx.x, b = blockIdx.y;
    const int q0 = qt * TQ_;
    const int bh = b * H_ + wave;
    const size_t sd = (size_t)bh * S_ * D_;
    const size_t ds = (size_t)bh * D_ * S_;

    // ---- Phase A: attention for head `wave`, 16 queries ----
    bf16x8 qf[2];
#pragma unroll
    for (int ks = 0; ks < 2; ks++)
        qf[ks] = *(const bf16x8*)(Qh + sd + (size_t)(q0 + r16) * D_ + ks * 32 + quad * 8);

    floatx4 zero = {0.f, 0.f, 0.f, 0.f};
    floatx4 O[4];          // PV acc: 4 d-groups
    float lsum[4];
#pragma unroll
    for (int j = 0; j < 4; j++) O[j] = zero;
#pragma unroll
    for (int r = 0; r < 4; r++) lsum[r] = 0.f;

    int lo = q0 - W_; if (lo < 0) lo = 0;
    int hi = q0 + TQ_ - 1 + W_; if (hi > S_ - 1) hi = S_ - 1;
    const int t_lo = lo >> 6, t_hi = hi >> 6;

    for (int t = t_lo; t <= t_hi; t++) {
        const int k0 = t * 64;
        floatx4 sa[4];
#pragma unroll
        for (int j = 0; j < 4; j++) sa[j] = zero;

#pragma unroll
        for (int ks = 0; ks < 2; ks++) {
            bf16x8 kf[4];
#pragma unroll
            for (int j = 0; j < 4; j++)
                kf[j] = *(const bf16x8*)(Kh + sd + (size_t)(k0 + j * 16 + r16) * D_ + ks * 32 + quad * 8);
#pragma unroll
            for (int j = 0; j < 4; j++)
                sa[j] = __builtin_amdgcn_mfma_f32_16x16x32_bf16(qf[ks], kf[j], sa[j], 0, 0, 0);
        }

        // p = exp(s/8 - M0) with band mask; per-lane row partials; P -> LDS
#pragma unroll
        for (int j = 0; j < 4; j++) {
            const int kc = k0 + j * 16 + r16;
#pragma unroll
            for (int r = 0; r < 4; r++) {
                const int q = q0 + quad * 4 + r;
                const bool valid = (unsigned)(kc - q + W_) <= (unsigned)(2 * W_);
                const float p = valid ? __expf(fmaf(sa[j][r], 0.125f, -M0_)) : 0.f;
                lsum[r] += p;
                Ps[wave][quad * 4 + r][j * 16 + r16] = f2b(p);
            }
        }
        // DS ops in-order per wave: Ps write->read within this wave is safe.

#pragma unroll
        for (int ks = 0; ks < 2; ks++) {
            bf16x8 pf, vf[4];
            pf = *(const bf16x8*)&Ps[wave][r16][ks * 32 + quad * 8];
#pragma unroll
            for (int j = 0; j < 4; j++)
                vf[j] = *(const bf16x8*)(Vth + ds + (size_t)(j * 16 + r16) * S_ + k0 + ks * 32 + quad * 8);
#pragma unroll
            for (int j = 0; j < 4; j++)
                O[j] = __builtin_amdgcn_mfma_f32_16x16x32_bf16(pf, vf[j], O[j], 0, 0, 0);
        }
    }

    // row-sum reduce over the 16 r16 lanes (bits 0-3 of lane)
    float inv[4];
#pragma unroll
    for (int r = 0; r < 4; r++) {
        float l = lsum[r];
#pragma unroll
        for (int off = 1; off < 16; off <<= 1) l += __shfl_xor(l, off, 64);
        inv[r] = 1.f / l;
    }

    // normalized AO tile -> LDS.  q row = quad*4+r, col = wave*64 + j*16 + r16
#pragma unroll
    for (int j = 0; j < 4; j++)
#pragma unroll
        for (int r = 0; r < 4; r++)
            AO[quad * 4 + r][wave * 64 + j * 16 + r16] = f2b(O[j][r] * inv[r]);

    __syncthreads();   // AO complete across all 8 heads

    // ---- Phase B: out tile [q0..q0+16) x [wave*64 .. +64) ----
    const int n0 = wave * 64;
    floatx4 acc[4];
#pragma unroll
    for (int j = 0; j < 4; j++) acc[j] = zero;

    for (int k0 = 0; k0 < HID_; k0 += 32) {
        bf16x8 af = *(const bf16x8*)&AO[r16][k0 + quad * 8];
        bf16x8 bfr[4];
#pragma unroll
        for (int j = 0; j < 4; j++) {
            const float4* wp = (const float4*)(Wo + (size_t)(n0 + j * 16 + r16) * HID_ + k0 + quad * 8);
            bfr[j] = cvt8(wp[0], wp[1]);
        }
#pragma unroll
        for (int j = 0; j < 4; j++)
            acc[j] = __builtin_amdgcn_mfma_f32_16x16x32_bf16(af, bfr[j], acc[j], 0, 0, 0);
    }

#pragma unroll
    for (int j = 0; j < 4; j++) {
        const int col = n0 + j * 16 + r16;
        const float bv = bo[col];
#pragma unroll
        for (int r = 0; r < 4; r++) {
            const int row = q0 + quad * 4 + r;
            out[(size_t)(b * S_ + row) * HID_ + col] = acc[j][r] + bv;
        }
    }
}

extern "C" void kernel_launch(void* const* d_in, const int* in_sizes, int n_in,
                              void* d_out, int out_size, void* d_ws, size_t ws_size,
                              hipStream_t stream) {
    const float* value = (const float*)d_in[0];
    const float* key_  = (const float*)d_in[1];
    const float* query = (const float*)d_in[2];
    const float* Wq = (const float*)d_in[3];
    const float* bq = (const float*)d_in[4];
    const float* Wk = (const float*)d_in[5];
    const float* bk = (const float*)d_in[6];
    const float* Wv = (const float*)d_in[7];
    const float* bv = (const float*)d_in[8];
    const float* Wo = (const float*)d_in[9];
    const float* bo = (const float*)d_in[10];

    // workspace (u16), 3E = 12 MB: Qh, Kh ([B,H,S,D]), Vth ([B,H,D,S])
    u16* P = (u16*)d_ws;

    qkv_fused_kernel<<<dim3(M_ / 128, HID_ / 64, 3), 128, 0, stream>>>(
        query, key_, value, Wq, Wk, Wv, bq, bk, bv, P);
    attn_out_kernel<<<dim3(S_ / TQ_, B_), 512, 0, stream>>>(
        P, P + E_, P + 2 * (size_t)E_, Wo, bo, (float*)d_out);
}